// Round 14
// baseline (194.562 us; speedup 1.0000x reference)
//
#include <hip/hip_runtime.h>
#include <hip/hip_bf16.h>
#include <hip/hip_fp8.h>

#define BB 4
#define CC 256
#define CI 128
#define NN 6272   // T*H*W = 8*28*28
#define LOG2E 1.4426950408889634f

typedef __attribute__((ext_vector_type(8))) __bf16 bf16x8;
typedef __attribute__((ext_vector_type(4))) float f32x4;
typedef __attribute__((ext_vector_type(16))) float f32x16;

__device__ __forceinline__ unsigned cvtpk_fp8(float a, float b) {
  unsigned r;
  asm("v_cvt_pk_fp8_f32 %0, %1, %2" : "=v"(r) : "v"(a), "v"(b));
  return r;
}

__device__ __forceinline__ unsigned char to_fp8(float v) {
  __hip_fp8_e4m3 t(v);
  return *reinterpret_cast<unsigned char*>(&t);
}

// piecewise-linear exp2 with fixed-M bias: p ~= 2^(s-4) = bitcast((s+123)*2^23).
// (single bias here; MFMA C-init is 0)
__device__ __forceinline__ float fexp2m(float s) {
  float t = (s + 123.0f) * 8388608.0f;
  return __int_as_float((int)t);
}

// ---------------- prep: fold weights/biases -> bf16, BN -> scale/shift ----------------
__global__ void nlb_prep(const float* __restrict__ Wg, const float* __restrict__ bg,
                         const float* __restrict__ Wt, const float* __restrict__ bt,
                         const float* __restrict__ Wp, const float* __restrict__ bp,
                         const float* __restrict__ Ww, const float* __restrict__ bw,
                         const float* __restrict__ gamma, const float* __restrict__ beta,
                         const float* __restrict__ rmean, const float* __restrict__ rvar,
                         __bf16* __restrict__ wall, float* __restrict__ ball,
                         __bf16* __restrict__ wwb, float* __restrict__ scale,
                         float* __restrict__ shift) {
  int idx = blockIdx.x * 256 + threadIdx.x;
  if (idx < 384 * 256) {
    int o = idx >> 8, c = idx & 255;
    float v, bv;
    if (o < 128)      { v = Wt[o * 256 + c] * LOG2E;  bv = bt[o] * LOG2E; }
    else if (o < 256) { v = Wp[(o - 128) * 256 + c]; bv = bp[o - 128]; }
    else              { v = Wg[(o - 256) * 256 + c]; bv = bg[o - 256]; }
    wall[idx] = (__bf16)v;
    if (c == 0) ball[o] = bv;
  } else if (idx < 384 * 256 + 256 * 128) {
    int i = idx - 384 * 256;
    wwb[i] = (__bf16)Ww[i];
  } else if (idx < 384 * 256 + 256 * 128 + 256) {
    int c = idx - (384 * 256 + 256 * 128);
    float inv = gamma[c] * rsqrtf(rvar[c] + 1e-5f);
    scale[c] = inv;
    shift[c] = (bw[c] - rmean[c]) * inv + beta[c];
  }
}

// ---------------- projections: Q row-major fp8; K/V as MFMA fragment streams ----------------
// VF key-permutation (within 16-key chunk): khi=(m>>2)&1, kb=(m&3)+4*(m>>3) so the PV
// A-fragment is lane-local (QK output regs 8ch..8ch+7 in order) -- no cross-lane exchange.
__launch_bounds__(256)
__global__ void nlb_proj(const float* __restrict__ x, const __bf16* __restrict__ wall,
                         const float* __restrict__ ball,
                         unsigned char* __restrict__ Q8, unsigned char* __restrict__ KF,
                         unsigned char* __restrict__ VF) {
  const int nb = blockIdx.x;          // 0..97
  const int b  = blockIdx.y;          // 0..3
  const int tid = threadIdx.x;
  const int lane = tid & 63, w = tid >> 6;
  const int n0 = nb * 64;
  const int r = lane & 15, g = lane >> 4;

  __shared__ __bf16 xl[64][40];

  const float* xb = x + (size_t)b * CC * NN;
  f32x4 acc[6][4] = {};

  const int snn = tid & 63;
  const int skg = tid >> 6;

  for (int k0 = 0; k0 < 256; k0 += 32) {
    bf16x8 tmp;
#pragma unroll
    for (int i = 0; i < 8; ++i)
      tmp[i] = (__bf16)xb[(size_t)(k0 + skg * 8 + i) * NN + n0 + snn];
    __syncthreads();
    *reinterpret_cast<bf16x8*>(&xl[snn][skg * 8]) = tmp;
    __syncthreads();

    bf16x8 bfrag[4];
#pragma unroll
    for (int j = 0; j < 4; ++j)
      bfrag[j] = *reinterpret_cast<const bf16x8*>(&xl[j * 16 + r][g * 8]);
#pragma unroll
    for (int mb = 0; mb < 6; ++mb) {
      bf16x8 afrag = *reinterpret_cast<const bf16x8*>(
          &wall[(size_t)(mb * 64 + w * 16 + r) * 256 + k0 + g * 8]);
#pragma unroll
      for (int j = 0; j < 4; ++j)
        acc[mb][j] = __builtin_amdgcn_mfma_f32_16x16x32_bf16(afrag, bfrag[j], acc[mb][j], 0, 0, 0);
    }
  }

  unsigned char* KFb = KF + (size_t)b * NN * CI;
  unsigned char* VFb = VF + (size_t)b * NN * CI;
#pragma unroll
  for (int mb = 0; mb < 6; ++mb) {
    const int m0 = mb * 64 + w * 16;
    if (m0 < 128) {                   // Q (row-major)
#pragma unroll
      for (int j = 0; j < 4; ++j) {
        int n = n0 + j * 16 + r;
        union { unsigned char bch[4]; unsigned u; } pk;
#pragma unroll
        for (int reg = 0; reg < 4; ++reg)
          pk.bch[reg] = to_fp8(acc[mb][j][reg] + ball[m0 + g * 4 + reg]);
        *reinterpret_cast<unsigned*>(&Q8[((size_t)b * NN + n) * CI + m0 + g * 4]) = pk.u;
      }
    } else if (m0 < 256) {            // K -> KF fragment stream
      const int kc = (m0 - 128) >> 4;
#pragma unroll
      for (int j = 0; j < 4; ++j) {
        int n = n0 + j * 16 + r;
        union { unsigned char bch[4]; unsigned u; } pk;
#pragma unroll
        for (int reg = 0; reg < 4; ++reg)
          pk.bch[reg] = to_fp8(acc[mb][j][reg] + ball[m0 + g * 4 + reg]);
        *reinterpret_cast<unsigned*>(
            &KFb[(size_t)(n >> 5) * 4096 + kc * 512 + (g >> 1) * 256 + (n & 31) * 8 + (g & 1) * 4]) = pk.u;
      }
    } else {                          // V -> VF fragment stream (key-permuted)
#pragma unroll
      for (int j = 0; j < 4; ++j) {
        int n = n0 + j * 16 + r;
        const int g32 = n >> 5, kl = n & 31;
        const int ch = kl >> 4, m = kl & 15;
        const int khi = (m >> 2) & 1, kb = (m & 3) + 4 * (m >> 3);
#pragma unroll
        for (int reg = 0; reg < 4; ++reg) {
          int o = m0 + g * 4 + reg;
          int ci = o - 256, cb = ci >> 5, cc = ci & 31;
          float v = acc[mb][j][reg] + ball[o];
          VFb[(size_t)g32 * 4096 + (ch * 4 + cb) * 512 + khi * 256 + cc * 8 + kb] = to_fp8(v);
        }
      }
    }
  }
}

// ---------------- flash attention: fp8, fixed-M, fragment-direct, QK||PV interleaved ----------------
// Per iter t: softmax(t) VALU, then ONE MFMA region alternating QK(t+1) (dependent chain)
// with PV(t) (independent) so the matrix pipe never starves on the chain latency.
__launch_bounds__(256, 2)
__global__ void nlb_attn(const unsigned char* __restrict__ Q8,
                         const unsigned char* __restrict__ KF,
                         const unsigned char* __restrict__ VF,
                         __bf16* __restrict__ Yp, float* __restrict__ Lp) {
  const int bid = blockIdx.x;                  // 0..1567
  const int pair = bid & 7;                    // XCD-resident (b, kh)
  const int b = pair >> 1, kh = pair & 1;
  const int q32 = bid >> 3;                    // 0..195
  const int tid = threadIdx.x, lane = tid & 63, w = tid >> 6;
  const int c = lane & 31, hi = lane >> 5;
  const int q0 = q32 * 32;

  const int t0 = kh * 98 + ((w * 98) >> 2);
  const int NT = (kh * 98 + (((w + 1) * 98) >> 2)) - t0;  // 24 or 25

  const unsigned char* Qb = Q8 + (size_t)b * NN * CI;
  const char* kfp = (const char*)(KF + (size_t)b * NN * CI) + (size_t)t0 * 4096;
  const char* vfp = (const char*)(VF + (size_t)b * NN * CI) + (size_t)t0 * 4096;

  __shared__ float scr[4096];                  // epilogue merge only (16KB)
  __shared__ float mls[64];

  long qf[8];
#pragma unroll
  for (int kc = 0; kc < 8; ++kc)
    qf[kc] = *reinterpret_cast<const long*>(&Qb[(size_t)(q0 + c) * CI + kc * 16 + hi * 8]);

  long kf[8], vf[8];
#pragma unroll
  for (int kc = 0; kc < 8; ++kc)
    kf[kc] = *reinterpret_cast<const long*>(kfp + kc * 512 + lane * 8);

  // QK(tile 0) -> sP (prologue; plain chain)
  f32x16 sP = {};
#pragma unroll
  for (int kc = 0; kc < 8; ++kc)
    sP = __builtin_amdgcn_mfma_f32_32x32x16_fp8_fp8(kf[kc], qf[kc], sP, 0, 0, 0);

#pragma unroll
  for (int i = 0; i < 8; ++i)
    vf[i] = *reinterpret_cast<const long*>(vfp + i * 512 + lane * 8);
  if (NT > 1) {
    kfp += 4096;
#pragma unroll
    for (int kc = 0; kc < 8; ++kc)
      kf[kc] = *reinterpret_cast<const long*>(kfp + kc * 512 + lane * 8);
  }

  f32x16 yacc[4] = {};
  float l_acc = 0.f;

#pragma unroll 2
  for (int t = 0; t < NT; ++t) {
    // ---- softmax(t): p = 2^(s-4), lane-local ----
    float s16[16];
    float ps = 0.f;
#pragma unroll
    for (int reg = 0; reg < 16; ++reg) {
      s16[reg] = fexp2m(sP[reg]);
      ps += s16[reg];
    }
    l_acc += ps;

    unsigned pw[4];
#pragma unroll
    for (int i = 0; i < 4; ++i) {
      unsigned lo  = cvtpk_fp8(s16[4 * i + 0], s16[4 * i + 1]);
      unsigned hi2 = cvtpk_fp8(s16[4 * i + 2], s16[4 * i + 3]);
      pw[i] = __builtin_amdgcn_perm(hi2, lo, 0x05040100);
    }
    const long paA = (long)(((unsigned long long)pw[1] << 32) | pw[0]);
    const long paB = (long)(((unsigned long long)pw[3] << 32) | pw[2]);

    // ---- MFMA region: QK(t+1) chain interleaved 1:1 with independent PV(t) ----
    // (last iter computes a discarded garbage QK: branchless tail)
    f32x16 sN = {};
    __builtin_amdgcn_s_setprio(1);
#pragma unroll
    for (int kc = 0; kc < 8; ++kc) {
      sN = __builtin_amdgcn_mfma_f32_32x32x16_fp8_fp8(kf[kc], qf[kc], sN, 0, 0, 0);
      yacc[kc & 3] = __builtin_amdgcn_mfma_f32_32x32x16_fp8_fp8(
          (kc < 4) ? paA : paB, vf[kc], yacc[kc & 3], 0, 0, 0);
    }
    __builtin_amdgcn_s_setprio(0);

    // ---- prefetches (consumed 1-2 iterations later) ----
    if (t + 2 < NT) {
      kfp += 4096;
#pragma unroll
      for (int kc = 0; kc < 8; ++kc)
        kf[kc] = *reinterpret_cast<const long*>(kfp + kc * 512 + lane * 8);
    }
    if (t + 1 < NT) {
      vfp += 4096;
#pragma unroll
      for (int i = 0; i < 8; ++i)
        vf[i] = *reinterpret_cast<const long*>(vfp + i * 512 + lane * 8);
    }

    sP = sN;                                   // rename under unroll-2
  }

  // ---- sequential 4-way in-block merge into wave 0; write UNNORMALIZED partials ----
  float l_full = l_acc + __shfl_xor(l_acc, 32);

#pragma unroll 1
  for (int src = 1; src < 4; ++src) {
    __syncthreads();
    if (w == src) {
#pragma unroll
      for (int cb = 0; cb < 4; ++cb)
#pragma unroll
        for (int reg = 0; reg < 16; ++reg)
          scr[(cb * 16 + reg) * 64 + lane] = yacc[cb][reg];
      mls[lane] = l_full;
    }
    __syncthreads();
    if (w == 0) {
#pragma unroll
      for (int cb = 0; cb < 4; ++cb)
#pragma unroll
        for (int reg = 0; reg < 16; ++reg)
          yacc[cb][reg] += scr[(cb * 16 + reg) * 64 + lane];
      l_full += mls[lane];
    }
  }
  if (w == 0) {
    if (hi == 0)
      Lp[(size_t)(kh * 4 + b) * NN + q0 + c] = l_full;
    __bf16* Yb = Yp + (size_t)(kh * 4 + b) * NN * CI;
#pragma unroll
    for (int cb = 0; cb < 4; ++cb) {
#pragma unroll
      for (int reg = 0; reg < 16; ++reg) {
        int qloc = (reg & 3) + 8 * (reg >> 2) + 4 * hi;
        Yb[(size_t)(q0 + qloc) * CI + cb * 32 + c] = (__bf16)yacc[cb][reg];
      }
    }
  }
}

// ---------------- output: z = (Ww @ (Yp0+Yp1))/(l0+l1)*scale + shift + x ----------------
__launch_bounds__(256)
__global__ void nlb_out(const __bf16* __restrict__ Yp, const float* __restrict__ Lp,
                        const __bf16* __restrict__ wwb,
                        const float* __restrict__ scale, const float* __restrict__ shift,
                        const float* __restrict__ x, float* __restrict__ out) {
  const int nb = blockIdx.x;
  const int mb = blockIdx.y;
  const int b  = blockIdx.z;
  const int tid = threadIdx.x, lane = tid & 63, w = tid >> 6;
  const int r = lane & 15, g = lane >> 4;
  const int n0 = nb * 64, c0 = mb * 64 + w * 16;

  const __bf16* Y0 = Yp + (size_t)b * NN * CI;
  const __bf16* Y1 = Yp + (size_t)(4 + b) * NN * CI;
  f32x4 acc[4] = {};
#pragma unroll
  for (int k0 = 0; k0 < 128; k0 += 32) {
    bf16x8 af = *reinterpret_cast<const bf16x8*>(&wwb[(size_t)(c0 + r) * CI + k0 + g * 8]);
#pragma unroll
    for (int j = 0; j < 4; ++j) {
      size_t yoff = (size_t)(n0 + j * 16 + r) * CI + k0 + g * 8;
      bf16x8 bf0 = *reinterpret_cast<const bf16x8*>(&Y0[yoff]);
      acc[j] = __builtin_amdgcn_mfma_f32_16x16x32_bf16(af, bf0, acc[j], 0, 0, 0);
      bf16x8 bf1 = *reinterpret_cast<const bf16x8*>(&Y1[yoff]);
      acc[j] = __builtin_amdgcn_mfma_f32_16x16x32_bf16(af, bf1, acc[j], 0, 0, 0);
    }
  }
  const float* xb = x + (size_t)b * CC * NN;
  float* ob = out + (size_t)b * CC * NN;
#pragma unroll
  for (int j = 0; j < 4; ++j) {
    int n = n0 + j * 16 + r;
    float il = 1.f / (Lp[(size_t)b * NN + n] + Lp[(size_t)(4 + b) * NN + n]);
#pragma unroll
    for (int reg = 0; reg < 4; ++reg) {
      int cc = c0 + g * 4 + reg;
      size_t off = (size_t)cc * NN + n;
      ob[off] = acc[j][reg] * (il * scale[cc]) + shift[cc] + xb[off];
    }
  }
}

extern "C" void kernel_launch(void* const* d_in, const int* in_sizes, int n_in,
                              void* d_out, int out_size, void* d_ws, size_t ws_size,
                              hipStream_t stream) {
  (void)in_sizes; (void)n_in; (void)out_size; (void)ws_size;
  const float* x     = (const float*)d_in[0];
  const float* Wg    = (const float*)d_in[1];
  const float* bg    = (const float*)d_in[2];
  const float* Wt    = (const float*)d_in[3];
  const float* bt    = (const float*)d_in[4];
  const float* Wp    = (const float*)d_in[5];
  const float* bp    = (const float*)d_in[6];
  const float* Ww    = (const float*)d_in[7];
  const float* bw    = (const float*)d_in[8];
  const float* gamma = (const float*)d_in[9];
  const float* beta  = (const float*)d_in[10];
  const float* rmean = (const float*)d_in[11];
  const float* rvar  = (const float*)d_in[12];
  float* out = (float*)d_out;

  char* ws = (char*)d_ws;
  __bf16* wall = (__bf16*)(ws + 0);                 // 196608
  float*  ball = (float*)(ws + 196608);             // 1536
  __bf16* wwb  = (__bf16*)(ws + 198144);            // 65536
  float*  scl  = (float*)(ws + 263680);             // 1024
  float*  shf  = (float*)(ws + 264704);             // 1024
  unsigned char* Q8 = (unsigned char*)(ws + 265728);            // 3211264
  unsigned char* KF = (unsigned char*)(ws + 3476992);           // 3211264
  unsigned char* VF = (unsigned char*)(ws + 6688256);           // 3211264
  __bf16* Yp   = (__bf16*)(ws + 9899520);                       // 12845056 (2 partials)
  float*  Lp   = (float*)(ws + 22744576);                       // 200704

  nlb_prep<<<513, 256, 0, stream>>>(Wg, bg, Wt, bt, Wp, bp, Ww, bw, gamma, beta,
                                    rmean, rvar, wall, ball, wwb, scl, shf);
  nlb_proj<<<dim3(98, 4), 256, 0, stream>>>(x, wall, ball, Q8, KF, VF);
  nlb_attn<<<1568, 256, 0, stream>>>(Q8, KF, VF, Yp, Lp);
  nlb_out<<<dim3(98, 4, 4), 256, 0, stream>>>(Yp, Lp, wwb, scl, shf, x, out);
}

// Round 15
// 173.719 us; speedup vs baseline: 1.1200x; 1.1200x over previous
//
#include <hip/hip_runtime.h>
#include <hip/hip_bf16.h>
#include <hip/hip_fp8.h>

#define BB 4
#define CC 256
#define CI 128
#define NN 6272   // T*H*W = 8*28*28
#define LOG2E 1.4426950408889634f

typedef __attribute__((ext_vector_type(8))) __bf16 bf16x8;
typedef __attribute__((ext_vector_type(4))) float f32x4;
typedef __attribute__((ext_vector_type(16))) float f32x16;

__device__ __forceinline__ unsigned cvtpk_fp8(float a, float b) {
  unsigned r;
  asm("v_cvt_pk_fp8_f32 %0, %1, %2" : "=v"(r) : "v"(a), "v"(b));
  return r;
}

__device__ __forceinline__ unsigned char to_fp8(float v) {
  __hip_fp8_e4m3 t(v);
  return *reinterpret_cast<unsigned char*>(&t);
}

// piecewise-linear exp2 with fixed-M bias: p ~= 2^(s-4) = bitcast((int)(s*2^23 + 123*2^23)).
// 2 full-rate VALU ops (v_fma_f32 + v_cvt_i32_f32).
__device__ __forceinline__ float fexp2m(float s) {
  return __int_as_float((int)fmaf(s, 8388608.0f, 1031798784.0f));
}

// ---------------- prep: fold weights/biases -> bf16, BN -> scale/shift ----------------
__global__ void nlb_prep(const float* __restrict__ Wg, const float* __restrict__ bg,
                         const float* __restrict__ Wt, const float* __restrict__ bt,
                         const float* __restrict__ Wp, const float* __restrict__ bp,
                         const float* __restrict__ Ww, const float* __restrict__ bw,
                         const float* __restrict__ gamma, const float* __restrict__ beta,
                         const float* __restrict__ rmean, const float* __restrict__ rvar,
                         __bf16* __restrict__ wall, float* __restrict__ ball,
                         __bf16* __restrict__ wwb, float* __restrict__ scale,
                         float* __restrict__ shift) {
  int idx = blockIdx.x * 256 + threadIdx.x;
  if (idx < 384 * 256) {
    int o = idx >> 8, c = idx & 255;
    float v, bv;
    if (o < 128)      { v = Wt[o * 256 + c] * LOG2E;  bv = bt[o] * LOG2E; }
    else if (o < 256) { v = Wp[(o - 128) * 256 + c]; bv = bp[o - 128]; }
    else              { v = Wg[(o - 256) * 256 + c]; bv = bg[o - 256]; }
    wall[idx] = (__bf16)v;
    if (c == 0) ball[o] = bv;
  } else if (idx < 384 * 256 + 256 * 128) {
    int i = idx - 384 * 256;
    wwb[i] = (__bf16)Ww[i];
  } else if (idx < 384 * 256 + 256 * 128 + 256) {
    int c = idx - (384 * 256 + 256 * 128);
    float inv = gamma[c] * rsqrtf(rvar[c] + 1e-5f);
    scale[c] = inv;
    shift[c] = (bw[c] - rmean[c]) * inv + beta[c];
  }
}

// ---------------- projections: Q row-major fp8; K/V as MFMA fragment streams ----------------
// VF key-permutation (within 16-key chunk): khi=(m>>2)&1, kb=(m&3)+4*(m>>3) so the PV
// A-fragment is lane-local (QK output regs 8ch..8ch+7 in order) -- no cross-lane exchange.
__launch_bounds__(256)
__global__ void nlb_proj(const float* __restrict__ x, const __bf16* __restrict__ wall,
                         const float* __restrict__ ball,
                         unsigned char* __restrict__ Q8, unsigned char* __restrict__ KF,
                         unsigned char* __restrict__ VF) {
  const int nb = blockIdx.x;          // 0..97
  const int b  = blockIdx.y;          // 0..3
  const int tid = threadIdx.x;
  const int lane = tid & 63, w = tid >> 6;
  const int n0 = nb * 64;
  const int r = lane & 15, g = lane >> 4;

  __shared__ __bf16 xl[64][40];

  const float* xb = x + (size_t)b * CC * NN;
  f32x4 acc[6][4] = {};

  const int snn = tid & 63;
  const int skg = tid >> 6;

  for (int k0 = 0; k0 < 256; k0 += 32) {
    bf16x8 tmp;
#pragma unroll
    for (int i = 0; i < 8; ++i)
      tmp[i] = (__bf16)xb[(size_t)(k0 + skg * 8 + i) * NN + n0 + snn];
    __syncthreads();
    *reinterpret_cast<bf16x8*>(&xl[snn][skg * 8]) = tmp;
    __syncthreads();

    bf16x8 bfrag[4];
#pragma unroll
    for (int j = 0; j < 4; ++j)
      bfrag[j] = *reinterpret_cast<const bf16x8*>(&xl[j * 16 + r][g * 8]);
#pragma unroll
    for (int mb = 0; mb < 6; ++mb) {
      bf16x8 afrag = *reinterpret_cast<const bf16x8*>(
          &wall[(size_t)(mb * 64 + w * 16 + r) * 256 + k0 + g * 8]);
#pragma unroll
      for (int j = 0; j < 4; ++j)
        acc[mb][j] = __builtin_amdgcn_mfma_f32_16x16x32_bf16(afrag, bfrag[j], acc[mb][j], 0, 0, 0);
    }
  }

  unsigned char* KFb = KF + (size_t)b * NN * CI;
  unsigned char* VFb = VF + (size_t)b * NN * CI;
#pragma unroll
  for (int mb = 0; mb < 6; ++mb) {
    const int m0 = mb * 64 + w * 16;
    if (m0 < 128) {                   // Q (row-major)
#pragma unroll
      for (int j = 0; j < 4; ++j) {
        int n = n0 + j * 16 + r;
        union { unsigned char bch[4]; unsigned u; } pk;
#pragma unroll
        for (int reg = 0; reg < 4; ++reg)
          pk.bch[reg] = to_fp8(acc[mb][j][reg] + ball[m0 + g * 4 + reg]);
        *reinterpret_cast<unsigned*>(&Q8[((size_t)b * NN + n) * CI + m0 + g * 4]) = pk.u;
      }
    } else if (m0 < 256) {            // K -> KF fragment stream
      const int kc = (m0 - 128) >> 4;
#pragma unroll
      for (int j = 0; j < 4; ++j) {
        int n = n0 + j * 16 + r;
        union { unsigned char bch[4]; unsigned u; } pk;
#pragma unroll
        for (int reg = 0; reg < 4; ++reg)
          pk.bch[reg] = to_fp8(acc[mb][j][reg] + ball[m0 + g * 4 + reg]);
        *reinterpret_cast<unsigned*>(
            &KFb[(size_t)(n >> 5) * 4096 + kc * 512 + (g >> 1) * 256 + (n & 31) * 8 + (g & 1) * 4]) = pk.u;
      }
    } else {                          // V -> VF fragment stream (key-permuted)
#pragma unroll
      for (int j = 0; j < 4; ++j) {
        int n = n0 + j * 16 + r;
        const int g32 = n >> 5, kl = n & 31;
        const int ch = kl >> 4, m = kl & 15;
        const int khi = (m >> 2) & 1, kb = (m & 3) + 4 * (m >> 3);
#pragma unroll
        for (int reg = 0; reg < 4; ++reg) {
          int o = m0 + g * 4 + reg;
          int ci = o - 256, cb = ci >> 5, cc = ci & 31;
          float v = acc[mb][j][reg] + ball[o];
          VFb[(size_t)g32 * 4096 + (ch * 4 + cb) * 512 + khi * 256 + cc * 8 + kb] = to_fp8(v);
        }
      }
    }
  }
}

// ---------------- flash attention: fp8, fixed-M, fragment-direct, 3 waves/SIMD ----------------
// Immediate-consume loop (QK -> softmax -> PV), single live s accumulator; register budget
// targeted at 3 waves/SIMD via __launch_bounds__(256, 3).
__launch_bounds__(256, 3)
__global__ void nlb_attn(const unsigned char* __restrict__ Q8,
                         const unsigned char* __restrict__ KF,
                         const unsigned char* __restrict__ VF,
                         __bf16* __restrict__ Yp, float* __restrict__ Lp) {
  const int bid = blockIdx.x;                  // 0..1567
  const int pair = bid & 7;                    // XCD-resident (b, kh)
  const int b = pair >> 1, kh = pair & 1;
  const int q32 = bid >> 3;                    // 0..195
  const int tid = threadIdx.x, lane = tid & 63, w = tid >> 6;
  const int c = lane & 31, hi = lane >> 5;
  const int q0 = q32 * 32;

  const int t0 = kh * 98 + ((w * 98) >> 2);
  const int NT = (kh * 98 + (((w + 1) * 98) >> 2)) - t0;  // 24 or 25

  const unsigned char* Qb = Q8 + (size_t)b * NN * CI;
  const char* kfp = (const char*)(KF + (size_t)b * NN * CI) + (size_t)t0 * 4096;
  const char* vfp = (const char*)(VF + (size_t)b * NN * CI) + (size_t)t0 * 4096;

  __shared__ float scr[4096];                  // epilogue merge only (16KB)
  __shared__ float mls[64];

  long qf[8];
#pragma unroll
  for (int kc = 0; kc < 8; ++kc)
    qf[kc] = *reinterpret_cast<const long*>(&Qb[(size_t)(q0 + c) * CI + kc * 16 + hi * 8]);

  long kf[8], vf[8];
#pragma unroll
  for (int kc = 0; kc < 8; ++kc)
    kf[kc] = *reinterpret_cast<const long*>(kfp + kc * 512 + lane * 8);
#pragma unroll
  for (int i = 0; i < 8; ++i)
    vf[i] = *reinterpret_cast<const long*>(vfp + i * 512 + lane * 8);

  f32x16 yacc[4] = {};
  float l_acc = 0.f;

  for (int t = 0; t < NT; ++t) {
    // ---- QK(t): single accumulator chain (latency covered by other waves) ----
    f32x16 s = {};
    __builtin_amdgcn_s_setprio(1);
#pragma unroll
    for (int kc = 0; kc < 8; ++kc)
      s = __builtin_amdgcn_mfma_f32_32x32x16_fp8_fp8(kf[kc], qf[kc], s, 0, 0, 0);
    __builtin_amdgcn_s_setprio(0);

    // prefetch K(t+1): has softmax+PV (~400cy) to complete
    if (t + 1 < NT) {
      kfp += 4096;
#pragma unroll
      for (int kc = 0; kc < 8; ++kc)
        kf[kc] = *reinterpret_cast<const long*>(kfp + kc * 512 + lane * 8);
    }

    // ---- softmax(t): p = 2^(s-4), lane-local, 2 ops/element ----
    float p16[16];
    float ps = 0.f;
#pragma unroll
    for (int reg = 0; reg < 16; ++reg) {
      p16[reg] = fexp2m(s[reg]);
      ps += p16[reg];
    }
    l_acc += ps;

    unsigned pw[4];
#pragma unroll
    for (int i = 0; i < 4; ++i) {
      unsigned lo  = cvtpk_fp8(p16[4 * i + 0], p16[4 * i + 1]);
      unsigned hi2 = cvtpk_fp8(p16[4 * i + 2], p16[4 * i + 3]);
      pw[i] = __builtin_amdgcn_perm(hi2, lo, 0x05040100);
    }

    // ---- PV(t): pa lane-local (key-permuted VF); 4 chains of 2 ----
    __builtin_amdgcn_s_setprio(1);
#pragma unroll
    for (int ch = 0; ch < 2; ++ch) {
      long pa = (long)(((unsigned long long)pw[ch * 2 + 1] << 32) | pw[ch * 2]);
#pragma unroll
      for (int cb = 0; cb < 4; ++cb)
        yacc[cb] = __builtin_amdgcn_mfma_f32_32x32x16_fp8_fp8(pa, vf[ch * 4 + cb], yacc[cb], 0, 0, 0);
    }
    __builtin_amdgcn_s_setprio(0);

    // prefetch V(t+1)
    if (t + 1 < NT) {
      vfp += 4096;
#pragma unroll
      for (int i = 0; i < 8; ++i)
        vf[i] = *reinterpret_cast<const long*>(vfp + i * 512 + lane * 8);
    }
  }

  // ---- sequential 4-way in-block merge into wave 0; write UNNORMALIZED partials ----
  float l_full = l_acc + __shfl_xor(l_acc, 32);

#pragma unroll 1
  for (int src = 1; src < 4; ++src) {
    __syncthreads();
    if (w == src) {
#pragma unroll
      for (int cb = 0; cb < 4; ++cb)
#pragma unroll
        for (int reg = 0; reg < 16; ++reg)
          scr[(cb * 16 + reg) * 64 + lane] = yacc[cb][reg];
      mls[lane] = l_full;
    }
    __syncthreads();
    if (w == 0) {
#pragma unroll
      for (int cb = 0; cb < 4; ++cb)
#pragma unroll
        for (int reg = 0; reg < 16; ++reg)
          yacc[cb][reg] += scr[(cb * 16 + reg) * 64 + lane];
      l_full += mls[lane];
    }
  }
  if (w == 0) {
    if (hi == 0)
      Lp[(size_t)(kh * 4 + b) * NN + q0 + c] = l_full;
    __bf16* Yb = Yp + (size_t)(kh * 4 + b) * NN * CI;
#pragma unroll
    for (int cb = 0; cb < 4; ++cb) {
#pragma unroll
      for (int reg = 0; reg < 16; ++reg) {
        int qloc = (reg & 3) + 8 * (reg >> 2) + 4 * hi;
        Yb[(size_t)(q0 + qloc) * CI + cb * 32 + c] = (__bf16)yacc[cb][reg];
      }
    }
  }
}

// ---------------- output: z = (Ww @ (Yp0+Yp1))/(l0+l1)*scale + shift + x ----------------
__launch_bounds__(256)
__global__ void nlb_out(const __bf16* __restrict__ Yp, const float* __restrict__ Lp,
                        const __bf16* __restrict__ wwb,
                        const float* __restrict__ scale, const float* __restrict__ shift,
                        const float* __restrict__ x, float* __restrict__ out) {
  const int nb = blockIdx.x;
  const int mb = blockIdx.y;
  const int b  = blockIdx.z;
  const int tid = threadIdx.x, lane = tid & 63, w = tid >> 6;
  const int r = lane & 15, g = lane >> 4;
  const int n0 = nb * 64, c0 = mb * 64 + w * 16;

  const __bf16* Y0 = Yp + (size_t)b * NN * CI;
  const __bf16* Y1 = Yp + (size_t)(4 + b) * NN * CI;
  f32x4 acc[4] = {};
#pragma unroll
  for (int k0 = 0; k0 < 128; k0 += 32) {
    bf16x8 af = *reinterpret_cast<const bf16x8*>(&wwb[(size_t)(c0 + r) * CI + k0 + g * 8]);
#pragma unroll
    for (int j = 0; j < 4; ++j) {
      size_t yoff = (size_t)(n0 + j * 16 + r) * CI + k0 + g * 8;
      bf16x8 bf0 = *reinterpret_cast<const bf16x8*>(&Y0[yoff]);
      acc[j] = __builtin_amdgcn_mfma_f32_16x16x32_bf16(af, bf0, acc[j], 0, 0, 0);
      bf16x8 bf1 = *reinterpret_cast<const bf16x8*>(&Y1[yoff]);
      acc[j] = __builtin_amdgcn_mfma_f32_16x16x32_bf16(af, bf1, acc[j], 0, 0, 0);
    }
  }
  const float* xb = x + (size_t)b * CC * NN;
  float* ob = out + (size_t)b * CC * NN;
#pragma unroll
  for (int j = 0; j < 4; ++j) {
    int n = n0 + j * 16 + r;
    float il = 1.f / (Lp[(size_t)b * NN + n] + Lp[(size_t)(4 + b) * NN + n]);
#pragma unroll
    for (int reg = 0; reg < 4; ++reg) {
      int cc = c0 + g * 4 + reg;
      size_t off = (size_t)cc * NN + n;
      ob[off] = acc[j][reg] * (il * scale[cc]) + shift[cc] + xb[off];
    }
  }
}

extern "C" void kernel_launch(void* const* d_in, const int* in_sizes, int n_in,
                              void* d_out, int out_size, void* d_ws, size_t ws_size,
                              hipStream_t stream) {
  (void)in_sizes; (void)n_in; (void)out_size; (void)ws_size;
  const float* x     = (const float*)d_in[0];
  const float* Wg    = (const float*)d_in[1];
  const float* bg    = (const float*)d_in[2];
  const float* Wt    = (const float*)d_in[3];
  const float* bt    = (const float*)d_in[4];
  const float* Wp    = (const float*)d_in[5];
  const float* bp    = (const float*)d_in[6];
  const float* Ww    = (const float*)d_in[7];
  const float* bw    = (const float*)d_in[8];
  const float* gamma = (const float*)d_in[9];
  const float* beta  = (const float*)d_in[10];
  const float* rmean = (const float*)d_in[11];
  const float* rvar  = (const float*)d_in[12];
  float* out = (float*)d_out;

  char* ws = (char*)d_ws;
  __bf16* wall = (__bf16*)(ws + 0);                 // 196608
  float*  ball = (float*)(ws + 196608);             // 1536
  __bf16* wwb  = (__bf16*)(ws + 198144);            // 65536
  float*  scl  = (float*)(ws + 263680);             // 1024
  float*  shf  = (float*)(ws + 264704);             // 1024
  unsigned char* Q8 = (unsigned char*)(ws + 265728);            // 3211264
  unsigned char* KF = (unsigned char*)(ws + 3476992);           // 3211264
  unsigned char* VF = (unsigned char*)(ws + 6688256);           // 3211264
  __bf16* Yp   = (__bf16*)(ws + 9899520);                       // 12845056 (2 partials)
  float*  Lp   = (float*)(ws + 22744576);                       // 200704

  nlb_prep<<<513, 256, 0, stream>>>(Wg, bg, Wt, bt, Wp, bp, Ww, bw, gamma, beta,
                                    rmean, rvar, wall, ball, wwb, scl, shf);
  nlb_proj<<<dim3(98, 4), 256, 0, stream>>>(x, wall, ball, Q8, KF, VF);
  nlb_attn<<<1568, 256, 0, stream>>>(Q8, KF, VF, Yp, Lp);
  nlb_out<<<dim3(98, 4, 4), 256, 0, stream>>>(Yp, Lp, wwb, scl, shf, x, out);
}